// Round 14
// baseline (229.250 us; speedup 1.0000x reference)
//
#include <hip/hip_runtime.h>

#define BB 8
#define NN 20000
#define EE 320000
#define DD 64
#define ROWS (BB*NN)
#define TILES (ROWS/16)   // 10000
#define EPS 1e-5f
#define CH 64  // readout chunks per batch

// Full fp16 storage, fp32 compute. Node-major: hH[n][b][d] -> flat n*512+b*64+d;
// row r=(n*8+b) is 64 contiguous halfs (128B). GEMM = f16 MFMA with pre-split
// hi+lo fp16 weights (split error ~2^-21); accumulation always fp32.
// Layer-1 aggregation: rank-1 recompute (gather 4B scalars from L2-resident x,
// re-encode per edge on VALU). r13 showed wave-per-node was s_load-latency-bound
// (~35us); now block-per-node, 4-wave split, 4-neighbor unroll (32 loads in
// flight), LDS reduce.

typedef __attribute__((ext_vector_type(4))) float float4v;
typedef __attribute__((ext_vector_type(8))) _Float16 half8v;

__device__ __forceinline__ int bcasti(int v, int l) {
  return __builtin_amdgcn_readlane(v, l);
}

// ---------------- encoder: hH = relu(x @ W_in + b_in) (fp16 out) + cnt zero ----------------
__global__ __launch_bounds__(256) void k_encoder(const float* __restrict__ x,
    const float* __restrict__ Win, const float* __restrict__ bin,
    _Float16* __restrict__ hH, int* __restrict__ cnt) {
  int idx = blockIdx.x * 256 + threadIdx.x;
  if (idx < NN) cnt[idx] = 0;  // stream-ordered before k_deg
  int g = idx * 8;  // 8 halfs per thread
  if (g < NN * 512) {
    int n = g >> 9;
    int b = (g >> 6) & 7;
    int d0 = g & 63;
    float xv = x[(size_t)b * NN + n];
    float4 w0 = *(const float4*)&Win[d0];
    float4 w1 = *(const float4*)&Win[d0 + 4];
    float4 b0 = *(const float4*)&bin[d0];
    float4 b1 = *(const float4*)&bin[d0 + 4];
    float o[8];
    o[0] = fmaf(xv, w0.x, b0.x); o[1] = fmaf(xv, w0.y, b0.y);
    o[2] = fmaf(xv, w0.z, b0.z); o[3] = fmaf(xv, w0.w, b0.w);
    o[4] = fmaf(xv, w1.x, b1.x); o[5] = fmaf(xv, w1.y, b1.y);
    o[6] = fmaf(xv, w1.z, b1.z); o[7] = fmaf(xv, w1.w, b1.w);
    half8v ho;
#pragma unroll
    for (int k = 0; k < 8; ++k) ho[k] = (_Float16)(o[k] > 0.f ? o[k] : 0.f);
    *(half8v*)&hH[g] = ho;
  }
}

// ---------------- degree + (blocks 0-7) weight pre-split ----------------
// Prep layout (halfs): (((m*2+p)*2+c)*4+t)*512 + l*8 + i
//   value = W_m[(c*32 + (l>>4)*8 + i)*64 + t*16 + (l&15)], p=0 hi / p=1 lo.
__global__ __launch_bounds__(256) void k_deg(const int* __restrict__ dst,
    int* __restrict__ cnt, const float* __restrict__ Ws1,
    const float* __restrict__ Wm1, const float* __restrict__ Ws2,
    const float* __restrict__ Wm2, _Float16* __restrict__ o1,
    _Float16* __restrict__ o2) {
  int e = blockIdx.x * 256 + threadIdx.x;
  if (e < EE) atomicAdd(&cnt[dst[e]], 1);
  int gid = e;
  if (gid < 2048) {
    int layer = gid >> 10;
    int slot = gid & 1023;  // (m,c,t,l)
    int m = slot >> 9;
    int c = (slot >> 8) & 1;
    int t = (slot >> 6) & 3;
    int l = slot & 63;
    const float* W = layer ? (m ? Wm2 : Ws2) : (m ? Wm1 : Ws1);
    _Float16* out = layer ? o2 : o1;
    int k0 = c * 32 + (l >> 4) * 8;
    int col = t * 16 + (l & 15);
    half8v ohi, olo;
#pragma unroll
    for (int i = 0; i < 8; ++i) {
      float w = W[(k0 + i) * DD + col];
      _Float16 hi = (_Float16)w;
      ohi[i] = hi;
      olo[i] = (_Float16)(w - (float)hi);
    }
    *(half8v*)&out[(((m * 2 + 0) * 2 + c) * 4 + t) * 512 + l * 8] = ohi;
    *(half8v*)&out[(((m * 2 + 1) * 2 + c) * 4 + t) * 512 + l * 8] = olo;
  }
}

// ---------------- exclusive scan: cnt -> rowptr, and cursor copy ----------------
__global__ __launch_bounds__(1024) void k_scan(const int* __restrict__ cnt,
                                               int* __restrict__ rowptr,
                                               int* __restrict__ cur) {
  __shared__ int part[1024];
  int t = threadIdx.x;
  const int PER = (NN + 1023) / 1024;  // 20
  int base = t * PER;
  int s = 0;
#pragma unroll
  for (int i = 0; i < PER; ++i) {
    int idx = base + i;
    s += (idx < NN) ? cnt[idx] : 0;
  }
  part[t] = s;
  __syncthreads();
  for (int off = 1; off < 1024; off <<= 1) {
    int v = (t >= off) ? part[t - off] : 0;
    __syncthreads();
    part[t] += v;
    __syncthreads();
  }
  int run = (t > 0) ? part[t - 1] : 0;
#pragma unroll
  for (int i = 0; i < PER; ++i) {
    int idx = base + i;
    if (idx <= NN) rowptr[idx] = run;
    if (idx < NN) cur[idx] = run;  // cursor pre-initialized to rowptr
    run += (idx < NN) ? cnt[idx] : 0;
  }
}

// ---------------- fill CSR buckets (cursor already = rowptr) ----------------
__global__ __launch_bounds__(256) void k_fill(const int* __restrict__ src,
    const int* __restrict__ dst, int* __restrict__ cur,
    int* __restrict__ nbr) {
  int e = blockIdx.x * 256 + threadIdx.x;
  if (e < EE) {
    int pos = atomicAdd(&cur[dst[e]], 1);
    nbr[pos] = src[e];
  }
}

// ---------------- layer-1 aggregation via rank-1 recompute (block/node) ----------------
// aggH[n][b][d] = (sum_{s in N(n)} relu(x[b,s]*Win[d]+bin[d])) / max(deg,1)
// Block per node; 4 waves each take a contiguous quarter of the neighbor
// list with 4-neighbor unroll (32 independent s_loads in flight), then one
// LDS reduction. Kills the r13 s_load latency chain.
__global__ __launch_bounds__(256) void k_agg1(const float* __restrict__ x,
    const float* __restrict__ Win, const float* __restrict__ bin,
    const int* __restrict__ rowptr, const int* __restrict__ nbr,
    _Float16* __restrict__ aggH) {
  __shared__ float red[4][BB][64];  // 8 KB
  int n = blockIdx.x;
  int lane = threadIdx.x & 63;  // lane = d
  int wv = threadIdx.x >> 6;
  int s0 = rowptr[n], s1 = rowptr[n + 1];
  int deg = s1 - s0;
  float w = Win[lane], bb = bin[lane];
  float acc[BB];
#pragma unroll
  for (int k = 0; k < BB; ++k) acc[k] = 0.f;
  // this wave's contiguous quarter
  int q = (deg + 3) >> 2;
  int qs = s0 + wv * q;
  int qe = qs + q;
  if (qe > s1) qe = s1;
  for (int base = qs; base < qe; base += 64) {
    int m = qe - base;
    if (m > 64) m = 64;
    int idxv = (base + lane < qe) ? nbr[base + lane] : 0;
    int j = 0;
    for (; j + 4 <= m; j += 4) {
      int sA = bcasti(idxv, j),     sB = bcasti(idxv, j + 1);
      int sC = bcasti(idxv, j + 2), sD = bcasti(idxv, j + 3);
      float xa[BB], xb[BB], xc[BB], xd[BB];
#pragma unroll
      for (int b = 0; b < BB; ++b) xa[b] = x[(size_t)b * NN + sA];
#pragma unroll
      for (int b = 0; b < BB; ++b) xb[b] = x[(size_t)b * NN + sB];
#pragma unroll
      for (int b = 0; b < BB; ++b) xc[b] = x[(size_t)b * NN + sC];
#pragma unroll
      for (int b = 0; b < BB; ++b) xd[b] = x[(size_t)b * NN + sD];
#pragma unroll
      for (int b = 0; b < BB; ++b) {
        float t0 = fmaxf(0.f, fmaf(xa[b], w, bb));
        float t1 = fmaxf(0.f, fmaf(xb[b], w, bb));
        float t2 = fmaxf(0.f, fmaf(xc[b], w, bb));
        float t3 = fmaxf(0.f, fmaf(xd[b], w, bb));
        acc[b] += (t0 + t1) + (t2 + t3);
      }
    }
    for (; j < m; ++j) {
      int sA = bcasti(idxv, j);
#pragma unroll
      for (int b = 0; b < BB; ++b) {
        acc[b] += fmaxf(0.f, fmaf(x[(size_t)b * NN + sA], w, bb));
      }
    }
  }
#pragma unroll
  for (int b = 0; b < BB; ++b) red[wv][b][lane] = acc[b];
  __syncthreads();
  if (wv == 0) {
    float iv = 1.0f / (float)(deg > 1 ? deg : 1);
#pragma unroll
    for (int b = 0; b < BB; ++b) {
      float s = (red[0][b][lane] + red[1][b][lane]) +
                (red[2][b][lane] + red[3][b][lane]);
      aggH[(size_t)n * 512 + b * 64 + lane] = (_Float16)(s * iv);
    }
  }
}

// ---------------- layer-2 pull aggregation fp16 -> fp16 (fp32 accum) ----------------
// At measured random-gather fabric ceiling (~3 TB/s miss path) — do not touch.
__global__ __launch_bounds__(256) void k_agg(const _Float16* __restrict__ hH,
    const int* __restrict__ rowptr, const int* __restrict__ nbr,
    _Float16* __restrict__ aggH) {
  int wid = (blockIdx.x * 256 + threadIdx.x) >> 6;  // wave per node
  int lane = threadIdx.x & 63;
  if (wid >= NN) return;
  int n = wid;
  int s0 = rowptr[n], s1 = rowptr[n + 1];
  float acc[8];
#pragma unroll
  for (int k = 0; k < 8; ++k) acc[k] = 0.f;
  for (int base = s0; base < s1; base += 64) {
    int m = s1 - base;
    if (m > 64) m = 64;
    int idxv = (base + lane < s1) ? nbr[base + lane] : 0;
    int j = 0;
    for (; j + 8 <= m; j += 8) {
      half8v v[8];
#pragma unroll
      for (int i = 0; i < 8; ++i) {
        int s = bcasti(idxv, j + i);
        v[i] = *(const half8v*)(hH + (size_t)s * 512 + lane * 8);
      }
#pragma unroll
      for (int k = 0; k < 8; ++k) {
        float t0 = (float)v[0][k] + (float)v[1][k];
        float t1 = (float)v[2][k] + (float)v[3][k];
        float t2 = (float)v[4][k] + (float)v[5][k];
        float t3 = (float)v[6][k] + (float)v[7][k];
        acc[k] += (t0 + t1) + (t2 + t3);
      }
    }
    for (; j + 4 <= m; j += 4) {
      half8v v[4];
#pragma unroll
      for (int i = 0; i < 4; ++i) {
        int s = bcasti(idxv, j + i);
        v[i] = *(const half8v*)(hH + (size_t)s * 512 + lane * 8);
      }
#pragma unroll
      for (int k = 0; k < 8; ++k) {
        acc[k] += ((float)v[0][k] + (float)v[1][k]) +
                  ((float)v[2][k] + (float)v[3][k]);
      }
    }
    for (; j < m; ++j) {
      int s = bcasti(idxv, j);
      half8v v = *(const half8v*)(hH + (size_t)s * 512 + lane * 8);
#pragma unroll
      for (int k = 0; k < 8; ++k) acc[k] += (float)v[k];
    }
  }
  int deg = s1 - s0;
  float iv = 1.0f / (float)(deg > 1 ? deg : 1);
  half8v o;
#pragma unroll
  for (int k = 0; k < 8; ++k) o[k] = (_Float16)(acc[k] * iv);
  *(half8v*)(aggH + (size_t)n * 512 + lane * 8) = o;
}

// ---------------- MFMA node update: z = h + relu(h@Ws + agg@Wm + bias); LN ----------------
// A = fp16 direct (hH/aggH); W = pre-split fp16 hi/lo staged via 8 coalesced
// b128 copies per thread. 1250 blocks: 5000 waves x exactly 2 tiles, all
// co-resident (5 blocks/CU), balanced.
// Frag layouts (m89/m91): A lane=(row=l&15, k=(l>>4)*8+j); B lane=(k,col);
// C/D lane,reg j -> row=(l>>4)*4+j, col=l&15.  32 MFMA / 16-row tile.
__global__ __launch_bounds__(256) void k_node_mfma(
    const _Float16* __restrict__ hH, const _Float16* __restrict__ aggH,
    const _Float16* __restrict__ Wsp, const float* __restrict__ bias,
    const float* __restrict__ g, const float* __restrict__ be,
    _Float16* __restrict__ outH) {
  __shared__ _Float16 ldsw[16384];  // 32 KB pre-split weights
  int tid = threadIdx.x;
  int lane = tid & 63;
  int cidx = lane & 15;
  int grp = lane >> 4;

  // stage pre-split weights: 2048 x 16B coalesced copies
  for (int i = tid; i < 2048; i += 256)
    *(half8v*)&ldsw[i * 8] = *(const half8v*)&Wsp[i * 8];
  __syncthreads();

  float bias_c[4], gam_c[4], bet_c[4];
#pragma unroll
  for (int t = 0; t < 4; ++t) {
    int c = t * 16 + cidx;
    bias_c[t] = bias[c];
    gam_c[t] = g[c];
    bet_c[t] = be[c];
  }

  int gwave = blockIdx.x * 4 + (tid >> 6);  // 0..4999
#pragma unroll
  for (int it = 0; it < 2; ++it) {
    int tile = gwave + it * 5000;
    int r0 = tile * 16;
    const _Float16* hp = hH + (size_t)(r0 + cidx) * DD;
    const _Float16* ap = aggH + (size_t)(r0 + cidx) * DD;
    half8v ah[2], am[2];
    ah[0] = *(const half8v*)(hp + grp * 8);
    ah[1] = *(const half8v*)(hp + 32 + grp * 8);
    am[0] = *(const half8v*)(ap + grp * 8);
    am[1] = *(const half8v*)(ap + 32 + grp * 8);

    float4v acc[4];
#pragma unroll
    for (int t = 0; t < 4; ++t) acc[t] = (float4v){0.f, 0.f, 0.f, 0.f};
#pragma unroll
    for (int t = 0; t < 4; ++t) {
#pragma unroll
      for (int c = 0; c < 2; ++c) {
        const half8v bsh = *(const half8v*)&ldsw[((0 + c) * 4 + t) * 512 + lane * 8];
        const half8v bsl = *(const half8v*)&ldsw[((2 + c) * 4 + t) * 512 + lane * 8];
        const half8v bmh = *(const half8v*)&ldsw[((4 + c) * 4 + t) * 512 + lane * 8];
        const half8v bml = *(const half8v*)&ldsw[((6 + c) * 4 + t) * 512 + lane * 8];
        acc[t] = __builtin_amdgcn_mfma_f32_16x16x32_f16(ah[c], bsh, acc[t], 0, 0, 0);
        acc[t] = __builtin_amdgcn_mfma_f32_16x16x32_f16(ah[c], bsl, acc[t], 0, 0, 0);
        acc[t] = __builtin_amdgcn_mfma_f32_16x16x32_f16(am[c], bmh, acc[t], 0, 0, 0);
        acc[t] = __builtin_amdgcn_mfma_f32_16x16x32_f16(am[c], bml, acc[t], 0, 0, 0);
      }
    }
    // epilogue: residual (fp16 h, L1-hot) + relu + LayerNorm, fp32 math
#pragma unroll
    for (int j = 0; j < 4; ++j) {
      int row = r0 + grp * 4 + j;
      const _Float16* hr = hH + (size_t)row * DD;
      float zz[4];
      float part = 0.f;
#pragma unroll
      for (int t = 0; t < 4; ++t) {
        float hv = (float)hr[t * 16 + cidx];
        float v = acc[t][j] + bias_c[t];
        v = v > 0.f ? v : 0.f;
        zz[t] = hv + v;
        part += zz[t];
      }
      part += __shfl_xor(part, 1);
      part += __shfl_xor(part, 2);
      part += __shfl_xor(part, 4);
      part += __shfl_xor(part, 8);
      float mu = part * (1.0f / 64.0f);
      float vs = 0.f;
#pragma unroll
      for (int t = 0; t < 4; ++t) {
        float d = zz[t] - mu;
        vs += d * d;
      }
      vs += __shfl_xor(vs, 1);
      vs += __shfl_xor(vs, 2);
      vs += __shfl_xor(vs, 4);
      vs += __shfl_xor(vs, 8);
      float inv = rsqrtf(vs * (1.0f / 64.0f) + EPS);
#pragma unroll
      for (int t = 0; t < 4; ++t) {
        float val = fmaf(gam_c[t] * (zz[t] - mu), inv, bet_c[t]);
        outH[(size_t)row * DD + t * 16 + cidx] = (_Float16)val;
      }
    }
  }
}

// ---------------- readout partials (fp16 in, fp32 accum) ----------------
__global__ __launch_bounds__(256) void k_reduce(const _Float16* __restrict__ hH,
    float* __restrict__ psum, float* __restrict__ pmax) {
  int lane = threadIdx.x & 63;
  int w = threadIdx.x >> 6;
  int b = blockIdx.x / CH;
  int chunk = blockIdx.x % CH;
  const int csz = (NN + CH - 1) / CH;  // 313
  int n0 = chunk * csz;
  int n1 = n0 + csz;
  if (n1 > NN) n1 = NN;
  float s = 0.f, m = -INFINITY;
  for (int n = n0 + w; n < n1; n += 4) {
    float v = (float)hH[(size_t)n * 512 + b * 64 + lane];
    s += v;
    m = fmaxf(m, v);
  }
  __shared__ float ls[4][DD], lm[4][DD];
  ls[w][lane] = s;
  lm[w][lane] = m;
  __syncthreads();
  if (w == 0) {
    float ss = ls[0][lane] + ls[1][lane] + ls[2][lane] + ls[3][lane];
    float mm = fmaxf(fmaxf(lm[0][lane], lm[1][lane]),
                     fmaxf(lm[2][lane], lm[3][lane]));
    psum[((size_t)b * CH + chunk) * DD + lane] = ss;
    pmax[((size_t)b * CH + chunk) * DD + lane] = mm;
  }
}

// ---------------- final: graph_emb + MLP head ----------------
__global__ __launch_bounds__(512) void k_final(const float* __restrict__ psum,
    const float* __restrict__ pmax, const float* __restrict__ Wh1,
    const float* __restrict__ bh1, const float* __restrict__ Wh2,
    const float* __restrict__ bh2, float* __restrict__ out) {
  __shared__ float emb[BB][2 * DD];
  __shared__ float hid[BB][DD];
  int t = threadIdx.x;
  int b = t >> 6, d = t & 63;
  float s = 0.f, m = -INFINITY;
  for (int c = 0; c < CH; ++c) {
    s += psum[((size_t)b * CH + c) * DD + d];
    m = fmaxf(m, pmax[((size_t)b * CH + c) * DD + d]);
  }
  emb[b][d] = s * (1.0f / (float)NN);
  emb[b][DD + d] = m;
  __syncthreads();
  float acc = bh1[d];
#pragma unroll
  for (int k = 0; k < 2 * DD; ++k) acc = fmaf(emb[b][k], Wh1[k * DD + d], acc);
  hid[b][d] = acc > 0.f ? acc : 0.f;
  __syncthreads();
  if (d == 0) {
    float o = bh2[0];
    for (int j = 0; j < DD; ++j) o = fmaf(hid[b][j], Wh2[j], o);
    out[b] = o;
  }
}

extern "C" void kernel_launch(void* const* d_in, const int* in_sizes, int n_in,
                              void* d_out, int out_size, void* d_ws, size_t ws_size,
                              hipStream_t stream) {
  const float* x    = (const float*)d_in[0];
  const int*   ei   = (const int*)d_in[1];
  const float* Win  = (const float*)d_in[2];
  const float* bin  = (const float*)d_in[3];
  const float* Ws1  = (const float*)d_in[4];
  const float* Wm1  = (const float*)d_in[5];
  const float* bias1= (const float*)d_in[6];
  const float* g1   = (const float*)d_in[7];
  const float* be1  = (const float*)d_in[8];
  const float* Ws2  = (const float*)d_in[9];
  const float* Wm2  = (const float*)d_in[10];
  const float* bias2= (const float*)d_in[11];
  const float* g2   = (const float*)d_in[12];
  const float* be2  = (const float*)d_in[13];
  const float* Wh1  = (const float*)d_in[14];
  const float* bh1  = (const float*)d_in[15];
  const float* Wh2  = (const float*)d_in[16];
  const float* bh2  = (const float*)d_in[17];
  float* out = (float*)d_out;

  const int* src = ei;
  const int* dst = ei + EE;

  char* ws = (char*)d_ws;
  size_t off = 0;
  auto carve = [&](size_t bytes) {
    void* p = ws + off;
    off = (off + bytes + 255) & ~(size_t)255;
    return p;
  };
  const size_t h16bytes = sizeof(_Float16) * (size_t)ROWS * DD;  // 20.48 MB
  _Float16* hA     = (_Float16*)carve(h16bytes);
  _Float16* hB     = (_Float16*)carve(h16bytes);
  _Float16* aggH   = (_Float16*)carve(h16bytes);
  _Float16* Wsp1   = (_Float16*)carve(sizeof(_Float16) * 16384);
  _Float16* Wsp2   = (_Float16*)carve(sizeof(_Float16) * 16384);
  int*      cnt    = (int*)carve(sizeof(int) * NN);
  int*      cur    = (int*)carve(sizeof(int) * NN);
  int*      rowptr = (int*)carve(sizeof(int) * (NN + 1));
  int*      nbr    = (int*)carve(sizeof(int) * EE);
  float*    psum   = (float*)carve(sizeof(float) * (size_t)BB * CH * DD);
  float*    pmax   = (float*)carve(sizeof(float) * (size_t)BB * CH * DD);

  const int NODE_BLOCKS = 1250;  // 5000 waves x 2 tiles, all co-resident

  // encoder (fp16 out, zeroes cnt)
  k_encoder<<<(NN * 512 / 8 + 255) / 256, 256, 0, stream>>>(x, Win, bin, hA, cnt);

  // CSR build + weight pre-split (fused into k_deg blocks 0-7)
  k_deg<<<(EE + 255) / 256, 256, 0, stream>>>(dst, cnt, Ws1, Wm1, Ws2, Wm2,
                                              Wsp1, Wsp2);
  k_scan<<<1, 1024, 0, stream>>>(cnt, rowptr, cur);
  k_fill<<<(EE + 255) / 256, 256, 0, stream>>>(src, dst, cur, nbr);

  // ---- layer 1: rank-1 recompute aggregation (block/node, 4-wave split) ----
  k_agg1<<<NN, 256, 0, stream>>>(x, Win, bin, rowptr, nbr, aggH);
  k_node_mfma<<<NODE_BLOCKS, 256, 0, stream>>>(hA, aggH, Wsp1, bias1, g1,
                                               be1, hB);

  // ---- layer 2: generic row gather (at structural fabric floor) ----
  k_agg<<<(NN + 3) / 4, 256, 0, stream>>>(hB, rowptr, nbr, aggH);
  k_node_mfma<<<NODE_BLOCKS, 256, 0, stream>>>(hB, aggH, Wsp2, bias2, g2,
                                               be2, hA);

  // ---- readout + head ----
  k_reduce<<<BB * CH, 256, 0, stream>>>(hA, psum, pmax);
  k_final<<<1, 512, 0, stream>>>(psum, pmax, Wh1, bh1, Wh2, bh2, out);
}

// Round 15
// 214.011 us; speedup vs baseline: 1.0712x; 1.0712x over previous
//
#include <hip/hip_runtime.h>

#define BB 8
#define NN 20000
#define EE 320000
#define DD 64
#define ROWS (BB*NN)
#define TILES (ROWS/16)   // 10000
#define EPS 1e-5f
#define CH 64  // readout chunks per batch

// Full fp16 storage, fp32 compute. Node-major: hH[n][b][d] -> flat n*512+b*64+d;
// row r=(n*8+b) is 64 contiguous halfs (128B). GEMM = f16 MFMA with pre-split
// hi+lo fp16 weights (split error ~2^-21); accumulation always fp32.
// Layer-1 aggregation: rank-1 recompute. r13/r14 fed x via readlane->s_load
// (SMEM path: <=15 outstanding, in-order -> latency-bound). Now the x-gather
// rides the VMEM path: per 8-neighbor group one per-lane global_load_dword
// (lane = nb*8+b) staged through 256B of wave-local LDS, consumed via
// broadcast ds_read_b128. Zero scalar loads.

typedef __attribute__((ext_vector_type(4))) float float4v;
typedef __attribute__((ext_vector_type(8))) _Float16 half8v;

__device__ __forceinline__ int bcasti(int v, int l) {
  return __builtin_amdgcn_readlane(v, l);
}

// ---------------- encoder: hH = relu(x @ W_in + b_in) (fp16 out) + cnt zero ----------------
__global__ __launch_bounds__(256) void k_encoder(const float* __restrict__ x,
    const float* __restrict__ Win, const float* __restrict__ bin,
    _Float16* __restrict__ hH, int* __restrict__ cnt) {
  int idx = blockIdx.x * 256 + threadIdx.x;
  if (idx < NN) cnt[idx] = 0;  // stream-ordered before k_deg
  int g = idx * 8;  // 8 halfs per thread
  if (g < NN * 512) {
    int n = g >> 9;
    int b = (g >> 6) & 7;
    int d0 = g & 63;
    float xv = x[(size_t)b * NN + n];
    float4 w0 = *(const float4*)&Win[d0];
    float4 w1 = *(const float4*)&Win[d0 + 4];
    float4 b0 = *(const float4*)&bin[d0];
    float4 b1 = *(const float4*)&bin[d0 + 4];
    float o[8];
    o[0] = fmaf(xv, w0.x, b0.x); o[1] = fmaf(xv, w0.y, b0.y);
    o[2] = fmaf(xv, w0.z, b0.z); o[3] = fmaf(xv, w0.w, b0.w);
    o[4] = fmaf(xv, w1.x, b1.x); o[5] = fmaf(xv, w1.y, b1.y);
    o[6] = fmaf(xv, w1.z, b1.z); o[7] = fmaf(xv, w1.w, b1.w);
    half8v ho;
#pragma unroll
    for (int k = 0; k < 8; ++k) ho[k] = (_Float16)(o[k] > 0.f ? o[k] : 0.f);
    *(half8v*)&hH[g] = ho;
  }
}

// ---------------- degree + (blocks 0-7) weight pre-split ----------------
// Prep layout (halfs): (((m*2+p)*2+c)*4+t)*512 + l*8 + i
//   value = W_m[(c*32 + (l>>4)*8 + i)*64 + t*16 + (l&15)], p=0 hi / p=1 lo.
__global__ __launch_bounds__(256) void k_deg(const int* __restrict__ dst,
    int* __restrict__ cnt, const float* __restrict__ Ws1,
    const float* __restrict__ Wm1, const float* __restrict__ Ws2,
    const float* __restrict__ Wm2, _Float16* __restrict__ o1,
    _Float16* __restrict__ o2) {
  int e = blockIdx.x * 256 + threadIdx.x;
  if (e < EE) atomicAdd(&cnt[dst[e]], 1);
  int gid = e;
  if (gid < 2048) {
    int layer = gid >> 10;
    int slot = gid & 1023;  // (m,c,t,l)
    int m = slot >> 9;
    int c = (slot >> 8) & 1;
    int t = (slot >> 6) & 3;
    int l = slot & 63;
    const float* W = layer ? (m ? Wm2 : Ws2) : (m ? Wm1 : Ws1);
    _Float16* out = layer ? o2 : o1;
    int k0 = c * 32 + (l >> 4) * 8;
    int col = t * 16 + (l & 15);
    half8v ohi, olo;
#pragma unroll
    for (int i = 0; i < 8; ++i) {
      float w = W[(k0 + i) * DD + col];
      _Float16 hi = (_Float16)w;
      ohi[i] = hi;
      olo[i] = (_Float16)(w - (float)hi);
    }
    *(half8v*)&out[(((m * 2 + 0) * 2 + c) * 4 + t) * 512 + l * 8] = ohi;
    *(half8v*)&out[(((m * 2 + 1) * 2 + c) * 4 + t) * 512 + l * 8] = olo;
  }
}

// ---------------- exclusive scan: cnt -> rowptr, and cursor copy ----------------
__global__ __launch_bounds__(1024) void k_scan(const int* __restrict__ cnt,
                                               int* __restrict__ rowptr,
                                               int* __restrict__ cur) {
  __shared__ int part[1024];
  int t = threadIdx.x;
  const int PER = (NN + 1023) / 1024;  // 20
  int base = t * PER;
  int s = 0;
#pragma unroll
  for (int i = 0; i < PER; ++i) {
    int idx = base + i;
    s += (idx < NN) ? cnt[idx] : 0;
  }
  part[t] = s;
  __syncthreads();
  for (int off = 1; off < 1024; off <<= 1) {
    int v = (t >= off) ? part[t - off] : 0;
    __syncthreads();
    part[t] += v;
    __syncthreads();
  }
  int run = (t > 0) ? part[t - 1] : 0;
#pragma unroll
  for (int i = 0; i < PER; ++i) {
    int idx = base + i;
    if (idx <= NN) rowptr[idx] = run;
    if (idx < NN) cur[idx] = run;  // cursor pre-initialized to rowptr
    run += (idx < NN) ? cnt[idx] : 0;
  }
}

// ---------------- fill CSR buckets (cursor already = rowptr) ----------------
__global__ __launch_bounds__(256) void k_fill(const int* __restrict__ src,
    const int* __restrict__ dst, int* __restrict__ cur,
    int* __restrict__ nbr) {
  int e = blockIdx.x * 256 + threadIdx.x;
  if (e < EE) {
    int pos = atomicAdd(&cur[dst[e]], 1);
    nbr[pos] = src[e];
  }
}

// ---------------- layer-1 aggregation via rank-1 recompute (VMEM gather) ----------------
// aggH[n][b][d] = (sum_{s in N(n)} relu(x[b,s]*Win[d]+bin[d])) / max(deg,1)
// Wave per node. Per 8-neighbor group: lane (nb=l>>3, b=l&7) vector-loads
// x[b*NN + s_nb] (per-lane addr via __shfl of the idx vector), parks 64
// scalars in wave-local LDS, then lane(=d) consumes via broadcast
// ds_read_b128 + 3 VALU per (nb,b). No scalar loads, no barrier.
__global__ __launch_bounds__(256) void k_agg1(const float* __restrict__ x,
    const float* __restrict__ Win, const float* __restrict__ bin,
    const int* __restrict__ rowptr, const int* __restrict__ nbr,
    _Float16* __restrict__ aggH) {
  __shared__ float xs[4][64];  // per-wave staging (256B/wave)
  int wid = (blockIdx.x * 256 + threadIdx.x) >> 6;  // wave per node
  int lane = threadIdx.x & 63;                      // consume phase: lane = d
  int wv = threadIdx.x >> 6;
  if (wid >= NN) return;
  int n = wid;
  int s0 = rowptr[n], s1 = rowptr[n + 1];
  int deg = s1 - s0;
  float w = Win[lane], bb = bin[lane];
  int myb = lane & 7;  // load phase: batch index
  float acc[BB];
#pragma unroll
  for (int k = 0; k < BB; ++k) acc[k] = 0.f;
  for (int base = s0; base < s1; base += 64) {
    int m = s1 - base;
    if (m > 64) m = 64;
    int idxv = (base + lane < s1) ? nbr[base + lane] : 0;
    for (int j = 0; j < m; j += 8) {
      // ---- load phase: neighbor j+(lane>>3), batch lane&7 ----
      int s = __shfl(idxv, j + (lane >> 3), 64);
      xs[wv][lane] = x[(size_t)myb * NN + s];  // VMEM gather, per-lane addr
      // same-wave RAW ordered by lgkmcnt (no barrier needed)
      int lim = m - j;
      if (lim > 8) lim = 8;
      for (int nb = 0; nb < lim; ++nb) {  // wave-uniform trip count
        float4 xlo = *(const float4*)&xs[wv][nb * 8];
        float4 xhi = *(const float4*)&xs[wv][nb * 8 + 4];
        acc[0] += fmaxf(0.f, fmaf(xlo.x, w, bb));
        acc[1] += fmaxf(0.f, fmaf(xlo.y, w, bb));
        acc[2] += fmaxf(0.f, fmaf(xlo.z, w, bb));
        acc[3] += fmaxf(0.f, fmaf(xlo.w, w, bb));
        acc[4] += fmaxf(0.f, fmaf(xhi.x, w, bb));
        acc[5] += fmaxf(0.f, fmaf(xhi.y, w, bb));
        acc[6] += fmaxf(0.f, fmaf(xhi.z, w, bb));
        acc[7] += fmaxf(0.f, fmaf(xhi.w, w, bb));
      }
    }
  }
  float iv = 1.0f / (float)(deg > 1 ? deg : 1);
#pragma unroll
  for (int b = 0; b < BB; ++b) {
    aggH[(size_t)n * 512 + b * 64 + lane] = (_Float16)(acc[b] * iv);
  }
}

// ---------------- layer-2 pull aggregation fp16 -> fp16 (fp32 accum) ----------------
// At measured random-gather fabric ceiling (~3 TB/s miss path) — do not touch.
__global__ __launch_bounds__(256) void k_agg(const _Float16* __restrict__ hH,
    const int* __restrict__ rowptr, const int* __restrict__ nbr,
    _Float16* __restrict__ aggH) {
  int wid = (blockIdx.x * 256 + threadIdx.x) >> 6;  // wave per node
  int lane = threadIdx.x & 63;
  if (wid >= NN) return;
  int n = wid;
  int s0 = rowptr[n], s1 = rowptr[n + 1];
  float acc[8];
#pragma unroll
  for (int k = 0; k < 8; ++k) acc[k] = 0.f;
  for (int base = s0; base < s1; base += 64) {
    int m = s1 - base;
    if (m > 64) m = 64;
    int idxv = (base + lane < s1) ? nbr[base + lane] : 0;
    int j = 0;
    for (; j + 8 <= m; j += 8) {
      half8v v[8];
#pragma unroll
      for (int i = 0; i < 8; ++i) {
        int s = bcasti(idxv, j + i);
        v[i] = *(const half8v*)(hH + (size_t)s * 512 + lane * 8);
      }
#pragma unroll
      for (int k = 0; k < 8; ++k) {
        float t0 = (float)v[0][k] + (float)v[1][k];
        float t1 = (float)v[2][k] + (float)v[3][k];
        float t2 = (float)v[4][k] + (float)v[5][k];
        float t3 = (float)v[6][k] + (float)v[7][k];
        acc[k] += (t0 + t1) + (t2 + t3);
      }
    }
    for (; j + 4 <= m; j += 4) {
      half8v v[4];
#pragma unroll
      for (int i = 0; i < 4; ++i) {
        int s = bcasti(idxv, j + i);
        v[i] = *(const half8v*)(hH + (size_t)s * 512 + lane * 8);
      }
#pragma unroll
      for (int k = 0; k < 8; ++k) {
        acc[k] += ((float)v[0][k] + (float)v[1][k]) +
                  ((float)v[2][k] + (float)v[3][k]);
      }
    }
    for (; j < m; ++j) {
      int s = bcasti(idxv, j);
      half8v v = *(const half8v*)(hH + (size_t)s * 512 + lane * 8);
#pragma unroll
      for (int k = 0; k < 8; ++k) acc[k] += (float)v[k];
    }
  }
  int deg = s1 - s0;
  float iv = 1.0f / (float)(deg > 1 ? deg : 1);
  half8v o;
#pragma unroll
  for (int k = 0; k < 8; ++k) o[k] = (_Float16)(acc[k] * iv);
  *(half8v*)(aggH + (size_t)n * 512 + lane * 8) = o;
}

// ---------------- MFMA node update: z = h + relu(h@Ws + agg@Wm + bias); LN ----------------
// A = fp16 direct (hH/aggH); W = pre-split fp16 hi/lo staged via 8 coalesced
// b128 copies per thread. 1250 blocks: 5000 waves x exactly 2 tiles, all
// co-resident (5 blocks/CU), balanced.
// Frag layouts (m89/m91): A lane=(row=l&15, k=(l>>4)*8+j); B lane=(k,col);
// C/D lane,reg j -> row=(l>>4)*4+j, col=l&15.  32 MFMA / 16-row tile.
__global__ __launch_bounds__(256) void k_node_mfma(
    const _Float16* __restrict__ hH, const _Float16* __restrict__ aggH,
    const _Float16* __restrict__ Wsp, const float* __restrict__ bias,
    const float* __restrict__ g, const float* __restrict__ be,
    _Float16* __restrict__ outH) {
  __shared__ _Float16 ldsw[16384];  // 32 KB pre-split weights
  int tid = threadIdx.x;
  int lane = tid & 63;
  int cidx = lane & 15;
  int grp = lane >> 4;

  // stage pre-split weights: 2048 x 16B coalesced copies
  for (int i = tid; i < 2048; i += 256)
    *(half8v*)&ldsw[i * 8] = *(const half8v*)&Wsp[i * 8];
  __syncthreads();

  float bias_c[4], gam_c[4], bet_c[4];
#pragma unroll
  for (int t = 0; t < 4; ++t) {
    int c = t * 16 + cidx;
    bias_c[t] = bias[c];
    gam_c[t] = g[c];
    bet_c[t] = be[c];
  }

  int gwave = blockIdx.x * 4 + (tid >> 6);  // 0..4999
#pragma unroll
  for (int it = 0; it < 2; ++it) {
    int tile = gwave + it * 5000;
    int r0 = tile * 16;
    const _Float16* hp = hH + (size_t)(r0 + cidx) * DD;
    const _Float16* ap = aggH + (size_t)(r0 + cidx) * DD;
    half8v ah[2], am[2];
    ah[0] = *(const half8v*)(hp + grp * 8);
    ah[1] = *(const half8v*)(hp + 32 + grp * 8);
    am[0] = *(const half8v*)(ap + grp * 8);
    am[1] = *(const half8v*)(ap + 32 + grp * 8);

    float4v acc[4];
#pragma unroll
    for (int t = 0; t < 4; ++t) acc[t] = (float4v){0.f, 0.f, 0.f, 0.f};
#pragma unroll
    for (int t = 0; t < 4; ++t) {
#pragma unroll
      for (int c = 0; c < 2; ++c) {
        const half8v bsh = *(const half8v*)&ldsw[((0 + c) * 4 + t) * 512 + lane * 8];
        const half8v bsl = *(const half8v*)&ldsw[((2 + c) * 4 + t) * 512 + lane * 8];
        const half8v bmh = *(const half8v*)&ldsw[((4 + c) * 4 + t) * 512 + lane * 8];
        const half8v bml = *(const half8v*)&ldsw[((6 + c) * 4 + t) * 512 + lane * 8];
        acc[t] = __builtin_amdgcn_mfma_f32_16x16x32_f16(ah[c], bsh, acc[t], 0, 0, 0);
        acc[t] = __builtin_amdgcn_mfma_f32_16x16x32_f16(ah[c], bsl, acc[t], 0, 0, 0);
        acc[t] = __builtin_amdgcn_mfma_f32_16x16x32_f16(am[c], bmh, acc[t], 0, 0, 0);
        acc[t] = __builtin_amdgcn_mfma_f32_16x16x32_f16(am[c], bml, acc[t], 0, 0, 0);
      }
    }
    // epilogue: residual (fp16 h, L1-hot) + relu + LayerNorm, fp32 math
#pragma unroll
    for (int j = 0; j < 4; ++j) {
      int row = r0 + grp * 4 + j;
      const _Float16* hr = hH + (size_t)row * DD;
      float zz[4];
      float part = 0.f;
#pragma unroll
      for (int t = 0; t < 4; ++t) {
        float hv = (float)hr[t * 16 + cidx];
        float v = acc[t][j] + bias_c[t];
        v = v > 0.f ? v : 0.f;
        zz[t] = hv + v;
        part += zz[t];
      }
      part += __shfl_xor(part, 1);
      part += __shfl_xor(part, 2);
      part += __shfl_xor(part, 4);
      part += __shfl_xor(part, 8);
      float mu = part * (1.0f / 64.0f);
      float vs = 0.f;
#pragma unroll
      for (int t = 0; t < 4; ++t) {
        float d = zz[t] - mu;
        vs += d * d;
      }
      vs += __shfl_xor(vs, 1);
      vs += __shfl_xor(vs, 2);
      vs += __shfl_xor(vs, 4);
      vs += __shfl_xor(vs, 8);
      float inv = rsqrtf(vs * (1.0f / 64.0f) + EPS);
#pragma unroll
      for (int t = 0; t < 4; ++t) {
        float val = fmaf(gam_c[t] * (zz[t] - mu), inv, bet_c[t]);
        outH[(size_t)row * DD + t * 16 + cidx] = (_Float16)val;
      }
    }
  }
}

// ---------------- readout partials (fp16 in, fp32 accum) ----------------
__global__ __launch_bounds__(256) void k_reduce(const _Float16* __restrict__ hH,
    float* __restrict__ psum, float* __restrict__ pmax) {
  int lane = threadIdx.x & 63;
  int w = threadIdx.x >> 6;
  int b = blockIdx.x / CH;
  int chunk = blockIdx.x % CH;
  const int csz = (NN + CH - 1) / CH;  // 313
  int n0 = chunk * csz;
  int n1 = n0 + csz;
  if (n1 > NN) n1 = NN;
  float s = 0.f, m = -INFINITY;
  for (int n = n0 + w; n < n1; n += 4) {
    float v = (float)hH[(size_t)n * 512 + b * 64 + lane];
    s += v;
    m = fmaxf(m, v);
  }
  __shared__ float ls[4][DD], lm[4][DD];
  ls[w][lane] = s;
  lm[w][lane] = m;
  __syncthreads();
  if (w == 0) {
    float ss = ls[0][lane] + ls[1][lane] + ls[2][lane] + ls[3][lane];
    float mm = fmaxf(fmaxf(lm[0][lane], lm[1][lane]),
                     fmaxf(lm[2][lane], lm[3][lane]));
    psum[((size_t)b * CH + chunk) * DD + lane] = ss;
    pmax[((size_t)b * CH + chunk) * DD + lane] = mm;
  }
}

// ---------------- final: graph_emb + MLP head ----------------
__global__ __launch_bounds__(512) void k_final(const float* __restrict__ psum,
    const float* __restrict__ pmax, const float* __restrict__ Wh1,
    const float* __restrict__ bh1, const float* __restrict__ Wh2,
    const float* __restrict__ bh2, float* __restrict__ out) {
  __shared__ float emb[BB][2 * DD];
  __shared__ float hid[BB][DD];
  int t = threadIdx.x;
  int b = t >> 6, d = t & 63;
  float s = 0.f, m = -INFINITY;
  for (int c = 0; c < CH; ++c) {
    s += psum[((size_t)b * CH + c) * DD + d];
    m = fmaxf(m, pmax[((size_t)b * CH + c) * DD + d]);
  }
  emb[b][d] = s * (1.0f / (float)NN);
  emb[b][DD + d] = m;
  __syncthreads();
  float acc = bh1[d];
#pragma unroll
  for (int k = 0; k < 2 * DD; ++k) acc = fmaf(emb[b][k], Wh1[k * DD + d], acc);
  hid[b][d] = acc > 0.f ? acc : 0.f;
  __syncthreads();
  if (d == 0) {
    float o = bh2[0];
    for (int j = 0; j < DD; ++j) o = fmaf(hid[b][j], Wh2[j], o);
    out[b] = o;
  }
}

extern "C" void kernel_launch(void* const* d_in, const int* in_sizes, int n_in,
                              void* d_out, int out_size, void* d_ws, size_t ws_size,
                              hipStream_t stream) {
  const float* x    = (const float*)d_in[0];
  const int*   ei   = (const int*)d_in[1];
  const float* Win  = (const float*)d_in[2];
  const float* bin  = (const float*)d_in[3];
  const float* Ws1  = (const float*)d_in[4];
  const float* Wm1  = (const float*)d_in[5];
  const float* bias1= (const float*)d_in[6];
  const float* g1   = (const float*)d_in[7];
  const float* be1  = (const float*)d_in[8];
  const float* Ws2  = (const float*)d_in[9];
  const float* Wm2  = (const float*)d_in[10];
  const float* bias2= (const float*)d_in[11];
  const float* g2   = (const float*)d_in[12];
  const float* be2  = (const float*)d_in[13];
  const float* Wh1  = (const float*)d_in[14];
  const float* bh1  = (const float*)d_in[15];
  const float* Wh2  = (const float*)d_in[16];
  const float* bh2  = (const float*)d_in[17];
  float* out = (float*)d_out;

  const int* src = ei;
  const int* dst = ei + EE;

  char* ws = (char*)d_ws;
  size_t off = 0;
  auto carve = [&](size_t bytes) {
    void* p = ws + off;
    off = (off + bytes + 255) & ~(size_t)255;
    return p;
  };
  const size_t h16bytes = sizeof(_Float16) * (size_t)ROWS * DD;  // 20.48 MB
  _Float16* hA     = (_Float16*)carve(h16bytes);
  _Float16* hB     = (_Float16*)carve(h16bytes);
  _Float16* aggH   = (_Float16*)carve(h16bytes);
  _Float16* Wsp1   = (_Float16*)carve(sizeof(_Float16) * 16384);
  _Float16* Wsp2   = (_Float16*)carve(sizeof(_Float16) * 16384);
  int*      cnt    = (int*)carve(sizeof(int) * NN);
  int*      cur    = (int*)carve(sizeof(int) * NN);
  int*      rowptr = (int*)carve(sizeof(int) * (NN + 1));
  int*      nbr    = (int*)carve(sizeof(int) * EE);
  float*    psum   = (float*)carve(sizeof(float) * (size_t)BB * CH * DD);
  float*    pmax   = (float*)carve(sizeof(float) * (size_t)BB * CH * DD);

  const int NODE_BLOCKS = 1250;  // 5000 waves x 2 tiles, all co-resident

  // encoder (fp16 out, zeroes cnt)
  k_encoder<<<(NN * 512 / 8 + 255) / 256, 256, 0, stream>>>(x, Win, bin, hA, cnt);

  // CSR build + weight pre-split (fused into k_deg blocks 0-7)
  k_deg<<<(EE + 255) / 256, 256, 0, stream>>>(dst, cnt, Ws1, Wm1, Ws2, Wm2,
                                              Wsp1, Wsp2);
  k_scan<<<1, 1024, 0, stream>>>(cnt, rowptr, cur);
  k_fill<<<(EE + 255) / 256, 256, 0, stream>>>(src, dst, cur, nbr);

  // ---- layer 1: rank-1 recompute aggregation (VMEM gather via LDS) ----
  k_agg1<<<(NN + 3) / 4, 256, 0, stream>>>(x, Win, bin, rowptr, nbr, aggH);
  k_node_mfma<<<NODE_BLOCKS, 256, 0, stream>>>(hA, aggH, Wsp1, bias1, g1,
                                               be1, hB);

  // ---- layer 2: generic row gather (at structural fabric floor) ----
  k_agg<<<(NN + 3) / 4, 256, 0, stream>>>(hB, rowptr, nbr, aggH);
  k_node_mfma<<<NODE_BLOCKS, 256, 0, stream>>>(hB, aggH, Wsp2, bias2, g2,
                                               be2, hA);

  // ---- readout + head ----
  k_reduce<<<BB * CH, 256, 0, stream>>>(hA, psum, pmax);
  k_final<<<1, 512, 0, stream>>>(psum, pmax, Wh1, bh1, Wh2, bh2, out);
}